// Round 1
// baseline (1566.164 us; speedup 1.0000x reference)
//
#include <hip/hip_runtime.h>
#include <hip/hip_bf16.h>
#include <math.h>

// ---------------------------------------------------------------------------
// Tiled direct stride-2 VALID conv1d, fp32.
// Block = 256 threads = 16 o-groups x 16 t-groups.
// Each block: one batch sample b, TT=64 output positions, all CO outputs.
// LDS: input span xs[CI][SPAN], weight chunk wbuf[IC][K][CO].
// Thread computes NO=CO/16 outputs x NT=4 positions (t interleaved by 16
// so LDS x-reads across lanes are stride-2 floats -> free 2-way aliasing).
// ---------------------------------------------------------------------------
template<int K, int CI, int CO, int IC, bool RELU>
__global__ __launch_bounds__(256)
void conv_tile(const float* __restrict__ x, const float* __restrict__ w,
               const float* __restrict__ bias, float* __restrict__ y,
               int Tin, int Tout)
{
    constexpr int TT   = 64;
    constexpr int SPAN = 2 * TT - 2 + K;   // input floats needed per channel
    constexpr int NO   = CO / 16;
    constexpr int NT   = TT / 16;

    extern __shared__ float smem[];
    float* xs   = smem;                    // CI * SPAN
    float* wbuf = smem + CI * SPAN;        // IC * K * CO

    const int tid = threadIdx.x;
    const int nT  = (Tout + TT - 1) / TT;
    const int b   = blockIdx.x / nT;
    const int t0  = (blockIdx.x % nT) * TT;
    const float* xb = x + (size_t)b * CI * Tin;

    // stage input span (clamped, zero-filled past Tin; only affects t>=Tout)
    for (int idx = tid; idx < CI * SPAN; idx += 256) {
        int i = idx / SPAN, s = idx - i * SPAN;
        int g = 2 * t0 + s;
        xs[idx] = (g < Tin) ? xb[(size_t)i * Tin + g] : 0.f;
    }

    const int og = tid >> 4;   // 0..15
    const int tg = tid & 15;   // 0..15

    float acc[NO][NT];
    #pragma unroll
    for (int oo = 0; oo < NO; oo++)
        #pragma unroll
        for (int j = 0; j < NT; j++) acc[oo][j] = 0.f;

    for (int i0 = 0; i0 < CI; i0 += IC) {
        __syncthreads();  // xs ready (first iter) / wbuf consumers done (later)
        // stage weights for input channels [i0, i0+IC), layout [di][k][o]
        for (int idx = tid; idx < IC * K * CO; idx += 256) {
            int o   = idx % CO;
            int rem = idx / CO;
            int di  = rem / K;
            int k   = rem - di * K;
            wbuf[idx] = w[((size_t)o * CI + i0 + di) * K + k];
        }
        __syncthreads();

        #pragma unroll
        for (int di = 0; di < IC; di++) {
            #pragma unroll
            for (int k = 0; k < K; k++) {
                float xv[NT];
                #pragma unroll
                for (int j = 0; j < NT; j++)
                    xv[j] = xs[(i0 + di) * SPAN + 2 * (tg + 16 * j) + k];
                const float* wp = &wbuf[(di * K + k) * CO + og * NO];
                #pragma unroll
                for (int oo = 0; oo < NO; oo++) {
                    float wv = wp[oo];
                    #pragma unroll
                    for (int j = 0; j < NT; j++)
                        acc[oo][j] = fmaf(wv, xv[j], acc[oo][j]);
                }
            }
        }
    }

    #pragma unroll
    for (int oo = 0; oo < NO; oo++) {
        int o = og * NO + oo;
        float bv = bias[o];
        #pragma unroll
        for (int j = 0; j < NT; j++) {
            int t = t0 + tg + 16 * j;
            if (t < Tout) {
                float v = acc[oo][j] + bv;
                if (RELU) v = fmaxf(v, 0.f);
                y[((size_t)b * CO + o) * Tout + t] = v;
            }
        }
    }
}

// AvgPool1d(k=2,s=2) followed by ReLU (reference order: relu(avgpool(x)))
__global__ void pool2_relu(const float* __restrict__ x, float* __restrict__ y,
                           int Tin, int Tout, int total)
{
    int idx = blockIdx.x * 256 + threadIdx.x;
    if (idx >= total) return;
    int t  = idx % Tout;
    int bc = idx / Tout;
    float a = x[(size_t)bc * Tin + 2 * t];
    float b = x[(size_t)bc * Tin + 2 * t + 1];
    float v = 0.5f * (a + b);
    y[idx] = fmaxf(v, 0.f);
}

// AdaptiveMaxPool1d(1) over per-sample valid prefix of the T7=14 frames
__global__ void masked_max(const float* __restrict__ y7, const int* __restrict__ lens,
                           float* __restrict__ feat)
{
    int idx = blockIdx.x * 256 + threadIdx.x;  // b*128 + o
    if (idx >= 64 * 128) return;
    int b = idx >> 7;
    int L = lens[b];
    L = (L - 10) / 2 + 1;
    L = (L - 5) / 2 + 1;
    L = (L - 5) / 2 + 1;
    L = (L - 5) / 2 + 1;
    L = L / 2;
    L = (L - 5) / 2 + 1;
    L = L / 2;
    L = (L - 5) / 2 + 1;
    L = (L - 3) / 2 + 1;   // >= 2 for len >= 2048
    const float* p = y7 + (size_t)idx * 14;
    float m = -INFINITY;
    for (int t = 0; t < L; t++) m = fmaxf(m, p[t]);
    feat[idx] = m;
}

// MLP head: 128 -> relu 128 -> relu 64 -> 5. One block per batch sample.
__global__ __launch_bounds__(128)
void head_mlp(const float* __restrict__ feat,
              const float* __restrict__ lw1, const float* __restrict__ lb1,
              const float* __restrict__ lw2, const float* __restrict__ lb2,
              const float* __restrict__ lw3, const float* __restrict__ lb3,
              float* __restrict__ out)
{
    __shared__ float f[128], h1[128], h2[64];
    int b = blockIdx.x, tid = threadIdx.x;
    f[tid] = feat[b * 128 + tid];
    __syncthreads();
    {
        float s = lb1[tid];
        for (int i = 0; i < 128; i++) s = fmaf(lw1[tid * 128 + i], f[i], s);
        h1[tid] = fmaxf(s, 0.f);
    }
    __syncthreads();
    if (tid < 64) {
        float s = lb2[tid];
        for (int i = 0; i < 128; i++) s = fmaf(lw2[tid * 128 + i], h1[i], s);
        h2[tid] = fmaxf(s, 0.f);
    }
    __syncthreads();
    if (tid < 5) {
        float s = lb3[tid];
        for (int i = 0; i < 64; i++) s = fmaf(lw3[tid * 64 + i], h2[i], s);
        out[b * 5 + tid] = s;
    }
}

extern "C" void kernel_launch(void* const* d_in, const int* in_sizes, int n_in,
                              void* d_out, int out_size, void* d_ws, size_t ws_size,
                              hipStream_t stream)
{
    const float* x    = (const float*)d_in[0];
    const int*   lens = (const int*)  d_in[1];
    const float* w1 = (const float*)d_in[2];   const float* b1 = (const float*)d_in[3];
    const float* w2 = (const float*)d_in[4];   const float* b2 = (const float*)d_in[5];
    const float* w3 = (const float*)d_in[6];   const float* b3 = (const float*)d_in[7];
    const float* w4 = (const float*)d_in[8];   const float* b4 = (const float*)d_in[9];
    const float* w5 = (const float*)d_in[10];  const float* b5 = (const float*)d_in[11];
    const float* w6 = (const float*)d_in[12];  const float* b6 = (const float*)d_in[13];
    const float* w7 = (const float*)d_in[14];  const float* b7 = (const float*)d_in[15];
    const float* lw1 = (const float*)d_in[16]; const float* lb1 = (const float*)d_in[17];
    const float* lw2 = (const float*)d_in[18]; const float* lb2 = (const float*)d_in[19];
    const float* lw3 = (const float*)d_in[20]; const float* lb3 = (const float*)d_in[21];
    float* out = (float*)d_out;
    float* ws  = (float*)d_ws;

    const int B = 64;
    // Sequence lengths through the stack
    // 8192 -> 4092 -> 2044 -> 1020 -> 508 -> 254 -> 125 -> 62 -> 29 -> 14

    // persistent workspace (floats)
    size_t off = 0;
    auto take = [&](size_t n) { size_t o = off; off += n; return o; };
    size_t o_y3  = take((size_t)B * 96 * 1020);
    size_t o_y4  = take((size_t)B * 96 * 508);
    size_t o_y4p = take((size_t)B * 96 * 254);
    size_t o_y5  = take((size_t)B * 96 * 125);
    size_t o_y5p = take((size_t)B * 96 * 62);
    size_t o_y6  = take((size_t)B * 96 * 29);
    size_t o_y7  = take((size_t)B * 128 * 14);
    size_t o_ft  = take((size_t)B * 128);
    size_t persist = off;

    // batch-chunk layers 1-2 scratch so peak fits ws_size
    int Bc = 64;
    while (Bc > 1) {
        size_t need = (persist + (size_t)Bc * 96 * (4092 + 2044)) * sizeof(float);
        if (need <= ws_size) break;
        Bc >>= 1;
    }
    size_t o_y1 = persist;
    size_t o_y2 = o_y1 + (size_t)Bc * 96 * 4092;

    // dynamic LDS sizes (floats -> bytes)
    size_t sm1 = (size_t)(40 * (128 - 2 + 10) + 8 * 10 * 96)  * 4;  // 52.5 KB
    size_t sm5 = (size_t)(96 * (128 - 2 + 5)  + 4 * 5  * 96)  * 4;  // 58.0 KB
    size_t sm7 = (size_t)(96 * (128 - 2 + 3)  + 4 * 3  * 128) * 4;  // 55.7 KB

    const int nchunks = 64 / Bc;
    for (int c = 0; c < nchunks; c++) {
        const float* xc  = x + (size_t)c * Bc * 40 * 8192;
        float*       y3c = ws + o_y3 + (size_t)c * Bc * 96 * 1020;
        conv_tile<10, 40, 96, 8, true ><<<dim3(Bc * 64), 256, sm1, stream>>>(xc,        w1, b1, ws + o_y1, 8192, 4092);
        conv_tile< 5, 96, 96, 4, true ><<<dim3(Bc * 32), 256, sm5, stream>>>(ws + o_y1, w2, b2, ws + o_y2, 4092, 2044);
        conv_tile< 5, 96, 96, 4, true ><<<dim3(Bc * 16), 256, sm5, stream>>>(ws + o_y2, w3, b3, y3c,       2044, 1020);
    }
    conv_tile< 5, 96, 96, 4, false><<<dim3(64 * 8), 256, sm5, stream>>>(ws + o_y3,  w4, b4, ws + o_y4, 1020, 508);
    pool2_relu<<<dim3((64 * 96 * 254 + 255) / 256), 256, 0, stream>>>(ws + o_y4, ws + o_y4p, 508, 254, 64 * 96 * 254);
    conv_tile< 5, 96, 96, 4, false><<<dim3(64 * 2), 256, sm5, stream>>>(ws + o_y4p, w5, b5, ws + o_y5, 254, 125);
    pool2_relu<<<dim3((64 * 96 * 62 + 255) / 256), 256, 0, stream>>>(ws + o_y5, ws + o_y5p, 125, 62, 64 * 96 * 62);
    conv_tile< 5, 96, 96, 4, true ><<<dim3(64), 256, sm5, stream>>>(ws + o_y5p, w6, b6, ws + o_y6, 62, 29);
    conv_tile< 3, 96, 128, 4, true><<<dim3(64), 256, sm7, stream>>>(ws + o_y6,  w7, b7, ws + o_y7, 29, 14);
    masked_max<<<dim3(32), 256, 0, stream>>>(ws + o_y7, lens, ws + o_ft);
    head_mlp<<<dim3(64), 128, 0, stream>>>(ws + o_ft, lw1, lb1, lw2, lb2, lw3, lb3, out);
}

// Round 2
// 966.941 us; speedup vs baseline: 1.6197x; 1.6197x over previous
//
#include <hip/hip_runtime.h>
#include <hip/hip_bf16.h>
#include <math.h>

// ---------------------------------------------------------------------------
// Direct stride-2 VALID conv1d, fp32, v2.
// Block = 256 threads = 4 waves. Wave w owns output channels
// [w*CO/4, (w+1)*CO/4); lane l owns output position t0+l (TT=64 per block).
// x tile staged in LDS once; per input channel each lane loads its K-tap
// stride-2 window into registers via float2 (b64, free 2-way bank aliasing)
// and reuses it across all K taps. Weights pre-repacked to [ci][k][o] so the
// per-(ci,k) weight block for a wave is CONTIGUOUS and WAVE-UNIFORM ->
// compiler emits s_load (SMEM pipe) -> inner loop is almost pure v_fmac_f32.
// ---------------------------------------------------------------------------
template<int K, int CI, int CO, bool RELU>
__global__ __launch_bounds__(256)
void conv_tile2(const float* __restrict__ x, const float* __restrict__ wr,
                const float* __restrict__ bias, float* __restrict__ y,
                int Tin, int Tout)
{
    constexpr int TT    = 64;
    constexpr int SPAN  = 2 * TT - 2 + K;        // input floats per channel
    constexpr int SPANP = (SPAN + 2) & ~1;       // even pad (+ slack for odd-K float2 overread)
    constexpr int NO    = CO / 4;                // outputs per wave

    __shared__ float xs[CI * SPANP];

    const int tid  = threadIdx.x;
    const int lane = tid & 63;
    const int wave = __builtin_amdgcn_readfirstlane(tid >> 6);

    const int nT = (Tout + TT - 1) / TT;
    const int b  = blockIdx.x / nT;
    const int t0 = (blockIdx.x % nT) * TT;
    const float* xb = x + (size_t)b * CI * Tin;

    // stage x tile (zero-fill pad and past-Tin; those only feed t >= Tout lanes)
    for (int idx = tid; idx < CI * SPANP; idx += 256) {
        int i = idx / SPANP, s = idx - i * SPANP;
        int g = 2 * t0 + s;
        xs[idx] = (s < SPAN && g < Tin) ? xb[(size_t)i * Tin + g] : 0.f;
    }
    __syncthreads();

    float acc[NO];
    #pragma unroll
    for (int oo = 0; oo < NO; oo++) acc[oo] = 0.f;

    const float* wq = wr + wave * NO;      // wave-uniform base into [ci][k][CO]
    const int xoff = 2 * lane;             // float2-aligned (8B)

    for (int ci = 0; ci < CI; ci++) {
        float xr[K + (K & 1)];
        #pragma unroll
        for (int p = 0; p < (K + 1) / 2; p++) {
            float2 v = *(const float2*)&xs[ci * SPANP + xoff + 2 * p];
            xr[2 * p]     = v.x;
            xr[2 * p + 1] = v.y;
        }
        #pragma unroll
        for (int k = 0; k < K; k++) {
            const float* wp = wq + (ci * K + k) * CO;   // uniform -> s_load
            float xv = xr[k];
            #pragma unroll
            for (int oo = 0; oo < NO; oo++)
                acc[oo] = fmaf(wp[oo], xv, acc[oo]);
        }
    }

    const int o0 = wave * NO;
    const int t  = t0 + lane;
    if (t < Tout) {
        #pragma unroll
        for (int oo = 0; oo < NO; oo++) {
            float v = acc[oo] + bias[o0 + oo];
            if (RELU) v = fmaxf(v, 0.f);
            y[((size_t)b * CO + o0 + oo) * Tout + t] = v;
        }
    }
}

// repack w[o][ci][k] -> wr[ci][k][o]
__global__ void repack_w(const float* __restrict__ w, float* __restrict__ wr,
                         int CI, int K, int CO, int total)
{
    int idx = blockIdx.x * 256 + threadIdx.x;
    if (idx >= total) return;
    int o = idx % CO; int rem = idx / CO; int k = rem % K; int ci = rem / K;
    wr[idx] = w[((size_t)o * CI + ci) * K + k];
}

// AvgPool1d(k=2,s=2) then ReLU
__global__ void pool2_relu(const float* __restrict__ x, float* __restrict__ y,
                           int Tin, int Tout, int total)
{
    int idx = blockIdx.x * 256 + threadIdx.x;
    if (idx >= total) return;
    int t  = idx % Tout;
    int bc = idx / Tout;
    float a = x[(size_t)bc * Tin + 2 * t];
    float b = x[(size_t)bc * Tin + 2 * t + 1];
    y[idx] = fmaxf(0.5f * (a + b), 0.f);
}

// AdaptiveMaxPool1d(1) over per-sample valid prefix of the 14 frames
__global__ void masked_max(const float* __restrict__ y7, const int* __restrict__ lens,
                           float* __restrict__ feat)
{
    int idx = blockIdx.x * 256 + threadIdx.x;  // b*128 + o
    if (idx >= 64 * 128) return;
    int b = idx >> 7;
    int L = lens[b];
    L = (L - 10) / 2 + 1;
    L = (L - 5) / 2 + 1;
    L = (L - 5) / 2 + 1;
    L = (L - 5) / 2 + 1;
    L = L / 2;
    L = (L - 5) / 2 + 1;
    L = L / 2;
    L = (L - 5) / 2 + 1;
    L = (L - 3) / 2 + 1;
    const float* p = y7 + (size_t)idx * 14;
    float m = -INFINITY;
    for (int t = 0; t < L; t++) m = fmaxf(m, p[t]);
    feat[idx] = m;
}

// MLP head: 128 -> relu 128 -> relu 64 -> 5. One block per batch sample.
__global__ __launch_bounds__(128)
void head_mlp(const float* __restrict__ feat,
              const float* __restrict__ lw1, const float* __restrict__ lb1,
              const float* __restrict__ lw2, const float* __restrict__ lb2,
              const float* __restrict__ lw3, const float* __restrict__ lb3,
              float* __restrict__ out)
{
    __shared__ float f[128], h1[128], h2[64];
    int b = blockIdx.x, tid = threadIdx.x;
    f[tid] = feat[b * 128 + tid];
    __syncthreads();
    {
        float s = lb1[tid];
        for (int i = 0; i < 128; i++) s = fmaf(lw1[tid * 128 + i], f[i], s);
        h1[tid] = fmaxf(s, 0.f);
    }
    __syncthreads();
    if (tid < 64) {
        float s = lb2[tid];
        for (int i = 0; i < 128; i++) s = fmaf(lw2[tid * 128 + i], h1[i], s);
        h2[tid] = fmaxf(s, 0.f);
    }
    __syncthreads();
    if (tid < 5) {
        float s = lb3[tid];
        for (int i = 0; i < 64; i++) s = fmaf(lw3[tid * 64 + i], h2[i], s);
        out[b * 5 + tid] = s;
    }
}

extern "C" void kernel_launch(void* const* d_in, const int* in_sizes, int n_in,
                              void* d_out, int out_size, void* d_ws, size_t ws_size,
                              hipStream_t stream)
{
    const float* x    = (const float*)d_in[0];
    const int*   lens = (const int*)  d_in[1];
    const float* w1 = (const float*)d_in[2];   const float* b1 = (const float*)d_in[3];
    const float* w2 = (const float*)d_in[4];   const float* b2 = (const float*)d_in[5];
    const float* w3 = (const float*)d_in[6];   const float* b3 = (const float*)d_in[7];
    const float* w4 = (const float*)d_in[8];   const float* b4 = (const float*)d_in[9];
    const float* w5 = (const float*)d_in[10];  const float* b5 = (const float*)d_in[11];
    const float* w6 = (const float*)d_in[12];  const float* b6 = (const float*)d_in[13];
    const float* w7 = (const float*)d_in[14];  const float* b7 = (const float*)d_in[15];
    const float* lw1 = (const float*)d_in[16]; const float* lb1 = (const float*)d_in[17];
    const float* lw2 = (const float*)d_in[18]; const float* lb2 = (const float*)d_in[19];
    const float* lw3 = (const float*)d_in[20]; const float* lb3 = (const float*)d_in[21];
    float* out = (float*)d_out;
    float* ws  = (float*)d_ws;

    const int B = 64;
    // 8192 -> 4092 -> 2044 -> 1020 -> 508 -> 254 -> 125 -> 62 -> 29 -> 14

    size_t off = 0;
    auto take = [&](size_t n) { size_t o = off; off += n; return o; };
    size_t o_y3  = take((size_t)B * 96 * 1020);
    size_t o_y4  = take((size_t)B * 96 * 508);
    size_t o_y4p = take((size_t)B * 96 * 254);
    size_t o_y5  = take((size_t)B * 96 * 125);
    size_t o_y5p = take((size_t)B * 96 * 62);
    size_t o_y6  = take((size_t)B * 96 * 29);
    size_t o_y7  = take((size_t)B * 128 * 14);
    size_t o_ft  = take((size_t)B * 128);
    // repacked weights
    size_t o_w1r = take(40 * 10 * 96);
    size_t o_w2r = take(96 * 5 * 96);
    size_t o_w3r = take(96 * 5 * 96);
    size_t o_w4r = take(96 * 5 * 96);
    size_t o_w5r = take(96 * 5 * 96);
    size_t o_w6r = take(96 * 5 * 96);
    size_t o_w7r = take(96 * 3 * 128);
    size_t persist = off;

    // batch-chunk layers 1-2 scratch so peak fits ws_size
    int Bc = 64;
    while (Bc > 1) {
        size_t need = (persist + (size_t)Bc * 96 * (4092 + 2044)) * sizeof(float);
        if (need <= ws_size) break;
        Bc >>= 1;
    }
    size_t o_y1 = persist;
    size_t o_y2 = o_y1 + (size_t)Bc * 96 * 4092;

    // repack all conv weights to [ci][k][o]
    auto rp = [&](const float* w, size_t o_wr, int CI, int K, int CO) {
        int total = CI * K * CO;
        repack_w<<<dim3((total + 255) / 256), 256, 0, stream>>>(w, ws + o_wr, CI, K, CO, total);
    };
    rp(w1, o_w1r, 40, 10, 96);
    rp(w2, o_w2r, 96, 5, 96);
    rp(w3, o_w3r, 96, 5, 96);
    rp(w4, o_w4r, 96, 5, 96);
    rp(w5, o_w5r, 96, 5, 96);
    rp(w6, o_w6r, 96, 5, 96);
    rp(w7, o_w7r, 96, 3, 128);

    const int nchunks = 64 / Bc;
    for (int c = 0; c < nchunks; c++) {
        const float* xc  = x + (size_t)c * Bc * 40 * 8192;
        float*       y3c = ws + o_y3 + (size_t)c * Bc * 96 * 1020;
        conv_tile2<10, 40, 96, true ><<<dim3(Bc * 64), 256, 0, stream>>>(xc,        ws + o_w1r, b1, ws + o_y1, 8192, 4092);
        conv_tile2< 5, 96, 96, true ><<<dim3(Bc * 32), 256, 0, stream>>>(ws + o_y1, ws + o_w2r, b2, ws + o_y2, 4092, 2044);
        conv_tile2< 5, 96, 96, true ><<<dim3(Bc * 16), 256, 0, stream>>>(ws + o_y2, ws + o_w3r, b3, y3c,       2044, 1020);
    }
    conv_tile2< 5, 96, 96, false><<<dim3(64 * 8), 256, 0, stream>>>(ws + o_y3,  ws + o_w4r, b4, ws + o_y4, 1020, 508);
    pool2_relu<<<dim3((64 * 96 * 254 + 255) / 256), 256, 0, stream>>>(ws + o_y4, ws + o_y4p, 508, 254, 64 * 96 * 254);
    conv_tile2< 5, 96, 96, false><<<dim3(64 * 2), 256, 0, stream>>>(ws + o_y4p, ws + o_w5r, b5, ws + o_y5, 254, 125);
    pool2_relu<<<dim3((64 * 96 * 62 + 255) / 256), 256, 0, stream>>>(ws + o_y5, ws + o_y5p, 125, 62, 64 * 96 * 62);
    conv_tile2< 5, 96, 96, true ><<<dim3(64), 256, 0, stream>>>(ws + o_y5p, ws + o_w6r, b6, ws + o_y6, 62, 29);
    conv_tile2< 3, 96, 128, true><<<dim3(64), 256, 0, stream>>>(ws + o_y6,  ws + o_w7r, b7, ws + o_y7, 29, 14);
    masked_max<<<dim3(32), 256, 0, stream>>>(ws + o_y7, lens, ws + o_ft);
    head_mlp<<<dim3(64), 128, 0, stream>>>(ws + o_ft, lw1, lb1, lw2, lb2, lw3, lb3, out);
}

// Round 3
// 676.923 us; speedup vs baseline: 2.3137x; 1.4284x over previous
//
#include <hip/hip_runtime.h>
#include <hip/hip_bf16.h>
#include <math.h>

// =============================================================================
// v3: conv1-4 as split-bf16 (hi+lo) implicit-GEMM on MFMA 16x16x32_bf16,
//     3 passes (Ah*Bh + Ah*Bl + Al*Bh) ~= fp32 accuracy (residual ~2^-17 rel).
//     K dim = CI * KP with taps padded to KP in {8,16} (zero weights) so each
//     quad's 8-tap run is contiguous within one input channel -> B-fragments
//     load straight from global hi/lo bf16 arrays as 4 aligned dwords.
//     A (weights) pre-packed to the exact LDS fragment image; staged with
//     global_load_lds(16B), double-buffered, one barrier per 2-K-step chunk.
// conv5-7 + pools + masked max + MLP head stay on the verified fp32 path.
// =============================================================================

typedef __attribute__((ext_vector_type(8))) short bf16x8;   // 8 bf16 in 4 VGPRs
typedef __attribute__((ext_vector_type(4))) float f32x4;

__device__ __forceinline__ unsigned int f2b(float f) {      // fp32 -> bf16 bits (RNE)
    unsigned int u = __float_as_uint(f);
    return (u + 0x7fffu + ((u >> 16) & 1u)) >> 16;
}
__device__ __forceinline__ float b2f(unsigned int h) { return __uint_as_float(h << 16); }

__device__ __forceinline__ void stage16(const void* g, void* l) {
    __builtin_amdgcn_global_load_lds(
        (const __attribute__((address_space(1))) unsigned int*)g,
        (__attribute__((address_space(3))) unsigned int*)l, 16, 0, 0);
}

// ---------------------------------------------------------------------------
// conv as MFMA GEMM. CO=96 fixed. Block = 256 thr = 4 waves in 2x2:
// wm in {0,1}: rows [48*wm, 48*wm+48) (3 m-tiles); wn: N-half of NB columns.
// A LDS image per K-step: [half][mt(6)][lane(64)][j(8)] bf16 (12KB); chunk =
// 2 steps (24KB) x double buffer = 48KB.
// B-frag: lane(quad q, l16) holds patch[k = q*8+j][t = tbase+16*nt], i.e.
// x[ci][2t+k0+j] with ci = kg0/KP, k0 = kg0%KP (even) -> 4 dword loads.
// ---------------------------------------------------------------------------
template<int KP, int KW, int CI, int NB, bool RELU, bool OUT_BF16>
__global__ __launch_bounds__(256)
void conv_mfma(const unsigned short* __restrict__ xh,
               const unsigned short* __restrict__ xl,
               const unsigned short* __restrict__ wpk,
               const float* __restrict__ bias,
               unsigned short* __restrict__ yh,
               unsigned short* __restrict__ yl,
               float* __restrict__ yf,
               int Tin, int Tout)
{
    constexpr int CO     = 96;
    constexpr int STEPS  = CI * KP / 32;     // K-steps of 32
    constexpr int CHUNKS = STEPS / 2;
    constexpr int NT_W   = NB / 32;          // n-tiles per wave

    __shared__ __align__(16) unsigned short As[2 * 12288];   // 48KB double buffer

    const int tid  = threadIdx.x;
    const int lane = tid & 63;
    const int wave = tid >> 6;
    const int wm   = wave >> 1, wn = wave & 1;
    const int quad = lane >> 4;
    const int l16  = lane & 15;

    const int nT = (Tout + NB - 1) / NB;
    const int b  = blockIdx.x / nT;
    const int t0 = (blockIdx.x % nT) * NB;

    const unsigned int* xbh = (const unsigned int*)(xh + (size_t)b * CI * Tin);
    const unsigned int* xbl = (const unsigned int*)(xl + (size_t)b * CI * Tin);

    f32x4 acc[3][NT_W];
    #pragma unroll
    for (int mt = 0; mt < 3; mt++)
        #pragma unroll
        for (int nt = 0; nt < NT_W; nt++) acc[mt][nt] = (f32x4)0.f;

    auto stage_chunk = [&](int c, int buf) {
        const char* g = (const char*)wpk + (size_t)c * 24576 + (size_t)lane * 16;
        char* l = (char*)As + (size_t)buf * 24576;
        #pragma unroll
        for (int i = 0; i < 6; i++) {
            int seg = i * 4 + wave;
            stage16(g + seg * 1024, l + seg * 1024);
        }
    };

    stage_chunk(0, 0);
    const int tbase = t0 + wn * (NT_W * 16) + l16;
    __syncthreads();

    for (int c = 0; c < CHUNKS; ++c) {
        const int buf = c & 1;
        if (c + 1 < CHUNKS) stage_chunk(c + 1, buf ^ 1);   // overlaps with compute
        const unsigned short* Ab = As + buf * 12288;
        #pragma unroll
        for (int s = 0; s < 2; ++s) {
            bf16x8 Ah[3], Al[3];
            #pragma unroll
            for (int mt = 0; mt < 3; ++mt) {
                int mg = wm * 3 + mt;
                Ah[mt] = *(const bf16x8*)&Ab[((s * 2 + 0) * 6 + mg) * 512 + lane * 8];
                Al[mt] = *(const bf16x8*)&Ab[((s * 2 + 1) * 6 + mg) * 512 + lane * 8];
            }
            int kg0  = (c * 2 + s) * 32 + quad * 8;
            int ci   = kg0 / KP;                 // KP pow2 -> shift
            int k0   = kg0 % KP;                 // even
            int uidx = ci * (Tin >> 1) + tbase + (k0 >> 1);
            const unsigned int* bh = xbh + uidx;
            const unsigned int* bl = xbl + uidx;
            #pragma unroll
            for (int nt = 0; nt < NT_W; ++nt) {
                union { unsigned int u[4]; bf16x8 v; } Bh, Bl;
                #pragma unroll
                for (int p = 0; p < 4; p++) {
                    Bh.u[p] = bh[nt * 16 + p];
                    Bl.u[p] = bl[nt * 16 + p];
                }
                #pragma unroll
                for (int mt = 0; mt < 3; ++mt)
                    acc[mt][nt] = __builtin_amdgcn_mfma_f32_16x16x32_bf16(Ah[mt], Bh.v, acc[mt][nt], 0, 0, 0);
                #pragma unroll
                for (int mt = 0; mt < 3; ++mt)
                    acc[mt][nt] = __builtin_amdgcn_mfma_f32_16x16x32_bf16(Ah[mt], Bl.v, acc[mt][nt], 0, 0, 0);
                #pragma unroll
                for (int mt = 0; mt < 3; ++mt)
                    acc[mt][nt] = __builtin_amdgcn_mfma_f32_16x16x32_bf16(Al[mt], Bh.v, acc[mt][nt], 0, 0, 0);
            }
        }
        __syncthreads();   // drains stage loads (vmcnt) + protects LDS reuse
    }

    // epilogue: C/D layout col=l16 (t), row = quad*4+reg (o within m-tile)
    #pragma unroll
    for (int mt = 0; mt < 3; ++mt) {
        #pragma unroll
        for (int r = 0; r < 4; ++r) {
            int o = wm * 48 + mt * 16 + quad * 4 + r;
            float bv = bias[o];
            #pragma unroll
            for (int nt = 0; nt < NT_W; ++nt) {
                int t = tbase + nt * 16;
                if (t < Tout) {
                    float v = acc[mt][nt][r] + bv;
                    if (RELU) v = fmaxf(v, 0.f);
                    size_t oidx = ((size_t)b * CO + o) * Tout + t;
                    if (OUT_BF16) {
                        unsigned int hb = f2b(v);
                        unsigned int lb = f2b(v - b2f(hb));
                        yh[oidx] = (unsigned short)hb;
                        yl[oidx] = (unsigned short)lb;
                    } else {
                        yf[oidx] = v;
                    }
                }
            }
        }
    }
}

// pack w[o][ci][k] -> MFMA A image: chunk c (24KB): [s][half][mt6][lane][j8]
template<int KP, int KW, int CI>
__global__ void repack_mfma(const float* __restrict__ w, unsigned short* __restrict__ wpk,
                            int total)
{
    int idx = blockIdx.x * 256 + threadIdx.x;
    if (idx >= total) return;
    int j = idx & 7, lane = (idx >> 3) & 63, g = idx >> 9;
    int c = g / 24, r = g % 24;
    int mt = r % 6, sh = r / 6;            // sh = s*2+half
    int half = sh & 1, s = sh >> 1;
    int S  = c * 2 + s;
    int kg = S * 32 + (lane >> 4) * 8 + j;
    int o  = mt * 16 + (lane & 15);
    int ci = kg / KP, k = kg % KP;
    float val = (k < KW) ? w[((size_t)o * CI + ci) * KW + k] : 0.f;
    unsigned int hb = f2b(val);
    unsigned short out_v;
    if (half == 0) out_v = (unsigned short)hb;
    else           out_v = (unsigned short)f2b(val - b2f(hb));
    wpk[idx] = out_v;
}

// fp32 -> (hi, lo) bf16 split, vectorized x4
__global__ void split_fp32(const float* __restrict__ x, unsigned short* __restrict__ h,
                           unsigned short* __restrict__ l, int n4)
{
    int i = blockIdx.x * 256 + threadIdx.x;
    if (i >= n4) return;
    float4 v = ((const float4*)x)[i];
    unsigned int h0 = f2b(v.x), h1 = f2b(v.y), h2 = f2b(v.z), h3 = f2b(v.w);
    ushort4 hv = make_ushort4((unsigned short)h0, (unsigned short)h1,
                              (unsigned short)h2, (unsigned short)h3);
    ushort4 lv = make_ushort4((unsigned short)f2b(v.x - b2f(h0)),
                              (unsigned short)f2b(v.y - b2f(h1)),
                              (unsigned short)f2b(v.z - b2f(h2)),
                              (unsigned short)f2b(v.w - b2f(h3)));
    ((ushort4*)h)[i] = hv;
    ((ushort4*)l)[i] = lv;
}

// ---------------------------------------------------------------------------
// fp32 tail path (verified round-2 kernels): conv5-7, pools, max, head
// ---------------------------------------------------------------------------
template<int K, int CI, int CO, bool RELU>
__global__ __launch_bounds__(256)
void conv_tile2(const float* __restrict__ x, const float* __restrict__ wr,
                const float* __restrict__ bias, float* __restrict__ y,
                int Tin, int Tout)
{
    constexpr int TT    = 64;
    constexpr int SPAN  = 2 * TT - 2 + K;
    constexpr int SPANP = (SPAN + 2) & ~1;
    constexpr int NO    = CO / 4;

    __shared__ float xs[CI * SPANP];

    const int tid  = threadIdx.x;
    const int lane = tid & 63;
    const int wave = __builtin_amdgcn_readfirstlane(tid >> 6);

    const int nT = (Tout + TT - 1) / TT;
    const int b  = blockIdx.x / nT;
    const int t0 = (blockIdx.x % nT) * TT;
    const float* xb = x + (size_t)b * CI * Tin;

    for (int idx = tid; idx < CI * SPANP; idx += 256) {
        int i = idx / SPANP, s = idx - i * SPANP;
        int g = 2 * t0 + s;
        xs[idx] = (s < SPAN && g < Tin) ? xb[(size_t)i * Tin + g] : 0.f;
    }
    __syncthreads();

    float acc[NO];
    #pragma unroll
    for (int oo = 0; oo < NO; oo++) acc[oo] = 0.f;

    const float* wq = wr + wave * NO;
    const int xoff = 2 * lane;

    for (int ci = 0; ci < CI; ci++) {
        float xr[K + (K & 1)];
        #pragma unroll
        for (int p = 0; p < (K + 1) / 2; p++) {
            float2 v = *(const float2*)&xs[ci * SPANP + xoff + 2 * p];
            xr[2 * p]     = v.x;
            xr[2 * p + 1] = v.y;
        }
        #pragma unroll
        for (int k = 0; k < K; k++) {
            const float* wp = wq + (ci * K + k) * CO;
            float xv = xr[k];
            #pragma unroll
            for (int oo = 0; oo < NO; oo++)
                acc[oo] = fmaf(wp[oo], xv, acc[oo]);
        }
    }

    const int o0 = wave * NO;
    const int t  = t0 + lane;
    if (t < Tout) {
        #pragma unroll
        for (int oo = 0; oo < NO; oo++) {
            float v = acc[oo] + bias[o0 + oo];
            if (RELU) v = fmaxf(v, 0.f);
            y[((size_t)b * CO + o0 + oo) * Tout + t] = v;
        }
    }
}

__global__ void repack_w(const float* __restrict__ w, float* __restrict__ wr,
                         int CI, int K, int CO, int total)
{
    int idx = blockIdx.x * 256 + threadIdx.x;
    if (idx >= total) return;
    int o = idx % CO; int rem = idx / CO; int k = rem % K; int ci = rem / K;
    wr[idx] = w[((size_t)o * CI + ci) * K + k];
}

__global__ void pool2_relu(const float* __restrict__ x, float* __restrict__ y,
                           int Tin, int Tout, int total)
{
    int idx = blockIdx.x * 256 + threadIdx.x;
    if (idx >= total) return;
    int t  = idx % Tout;
    int bc = idx / Tout;
    float a = x[(size_t)bc * Tin + 2 * t];
    float b = x[(size_t)bc * Tin + 2 * t + 1];
    y[idx] = fmaxf(0.5f * (a + b), 0.f);
}

__global__ void masked_max(const float* __restrict__ y7, const int* __restrict__ lens,
                           float* __restrict__ feat)
{
    int idx = blockIdx.x * 256 + threadIdx.x;
    if (idx >= 64 * 128) return;
    int b = idx >> 7;
    int L = lens[b];
    L = (L - 10) / 2 + 1;
    L = (L - 5) / 2 + 1;
    L = (L - 5) / 2 + 1;
    L = (L - 5) / 2 + 1;
    L = L / 2;
    L = (L - 5) / 2 + 1;
    L = L / 2;
    L = (L - 5) / 2 + 1;
    L = (L - 3) / 2 + 1;
    const float* p = y7 + (size_t)idx * 14;
    float m = -INFINITY;
    for (int t = 0; t < L; t++) m = fmaxf(m, p[t]);
    feat[idx] = m;
}

__global__ __launch_bounds__(128)
void head_mlp(const float* __restrict__ feat,
              const float* __restrict__ lw1, const float* __restrict__ lb1,
              const float* __restrict__ lw2, const float* __restrict__ lb2,
              const float* __restrict__ lw3, const float* __restrict__ lb3,
              float* __restrict__ out)
{
    __shared__ float f[128], h1[128], h2[64];
    int b = blockIdx.x, tid = threadIdx.x;
    f[tid] = feat[b * 128 + tid];
    __syncthreads();
    {
        float s = lb1[tid];
        for (int i = 0; i < 128; i++) s = fmaf(lw1[tid * 128 + i], f[i], s);
        h1[tid] = fmaxf(s, 0.f);
    }
    __syncthreads();
    if (tid < 64) {
        float s = lb2[tid];
        for (int i = 0; i < 128; i++) s = fmaf(lw2[tid * 128 + i], h1[i], s);
        h2[tid] = fmaxf(s, 0.f);
    }
    __syncthreads();
    if (tid < 5) {
        float s = lb3[tid];
        for (int i = 0; i < 64; i++) s = fmaf(lw3[tid * 64 + i], h2[i], s);
        out[b * 5 + tid] = s;
    }
}

extern "C" void kernel_launch(void* const* d_in, const int* in_sizes, int n_in,
                              void* d_out, int out_size, void* d_ws, size_t ws_size,
                              hipStream_t stream)
{
    const float* x    = (const float*)d_in[0];
    const int*   lens = (const int*)  d_in[1];
    const float* w1 = (const float*)d_in[2];   const float* b1 = (const float*)d_in[3];
    const float* w2 = (const float*)d_in[4];   const float* b2 = (const float*)d_in[5];
    const float* w3 = (const float*)d_in[6];   const float* b3 = (const float*)d_in[7];
    const float* w4 = (const float*)d_in[8];   const float* b4 = (const float*)d_in[9];
    const float* w5 = (const float*)d_in[10];  const float* b5 = (const float*)d_in[11];
    const float* w6 = (const float*)d_in[12];  const float* b6 = (const float*)d_in[13];
    const float* w7 = (const float*)d_in[14];  const float* b7 = (const float*)d_in[15];
    const float* lw1 = (const float*)d_in[16]; const float* lb1 = (const float*)d_in[17];
    const float* lw2 = (const float*)d_in[18]; const float* lb2 = (const float*)d_in[19];
    const float* lw3 = (const float*)d_in[20]; const float* lb3 = (const float*)d_in[21];
    float* out = (float*)d_out;
    char*  W   = (char*)d_ws;

    // lengths: 8192 -> 4092 -> 2044 -> 1020 -> 508 -> 254 -> 125 -> 62 -> 29 -> 14
    size_t off = 0;
    auto take = [&](size_t bytes) {
        size_t o = off; off = (off + bytes + 255) & ~(size_t)255; return o;
    };
    // persistent buffers
    size_t o_y3h = take((size_t)64 * 96 * 1020 * 2 + 4096);
    size_t o_y3l = take((size_t)64 * 96 * 1020 * 2 + 4096);
    size_t o_y4  = take((size_t)64 * 96 * 508 * 4);
    size_t o_y4p = take((size_t)64 * 96 * 254 * 4);
    size_t o_y5  = take((size_t)64 * 96 * 125 * 4);
    size_t o_y5p = take((size_t)64 * 96 * 62 * 4);
    size_t o_y6  = take((size_t)64 * 96 * 29 * 4);
    size_t o_y7  = take((size_t)64 * 128 * 14 * 4);
    size_t o_ft  = take((size_t)64 * 128 * 4);
    size_t o_wp1 = take((size_t)640 * 192 * 2);      // 96 x 640 x 2 halves bf16
    size_t o_wp2 = take((size_t)768 * 192 * 2);
    size_t o_wp3 = take((size_t)768 * 192 * 2);
    size_t o_wp4 = take((size_t)768 * 192 * 2);
    size_t o_w5r = take((size_t)96 * 5 * 96 * 4);
    size_t o_w6r = take((size_t)96 * 5 * 96 * 4);
    size_t o_w7r = take((size_t)96 * 3 * 128 * 4);
    size_t persist = off;

    // batch-chunked region (x split + y1 + y2 hi/lo)
    auto chunk_bytes = [&](int Bc) -> size_t {
        size_t s = 0;
        s += 2 * (((size_t)Bc * 40 * 8192 + 2048) * 2 + 256);
        s += 2 * (((size_t)Bc * 96 * 4092 + 2048) * 2 + 256);
        s += 2 * (((size_t)Bc * 96 * 2044 + 2048) * 2 + 256);
        return s;
    };
    int Bc = 64;
    while (Bc > 1 && persist + chunk_bytes(Bc) > ws_size) Bc >>= 1;
    size_t o_xh  = take(((size_t)Bc * 40 * 8192 + 2048) * 2);
    size_t o_xl  = take(((size_t)Bc * 40 * 8192 + 2048) * 2);
    size_t o_y1h = take(((size_t)Bc * 96 * 4092 + 2048) * 2);
    size_t o_y1l = take(((size_t)Bc * 96 * 4092 + 2048) * 2);
    size_t o_y2h = take(((size_t)Bc * 96 * 2044 + 2048) * 2);
    size_t o_y2l = take(((size_t)Bc * 96 * 2044 + 2048) * 2);

    auto US = [&](size_t o) { return (unsigned short*)(W + o); };
    auto FP = [&](size_t o) { return (float*)(W + o); };

    // weight packing (re-done every call; tiny)
    {
        int t1 = 640 * 192;
        repack_mfma<16, 10, 40><<<dim3((t1 + 255) / 256), 256, 0, stream>>>(w1, US(o_wp1), t1);
        int t2 = 768 * 192;
        repack_mfma< 8,  5, 96><<<dim3((t2 + 255) / 256), 256, 0, stream>>>(w2, US(o_wp2), t2);
        repack_mfma< 8,  5, 96><<<dim3((t2 + 255) / 256), 256, 0, stream>>>(w3, US(o_wp3), t2);
        repack_mfma< 8,  5, 96><<<dim3((t2 + 255) / 256), 256, 0, stream>>>(w4, US(o_wp4), t2);
        int t5 = 96 * 5 * 96;
        repack_w<<<dim3((t5 + 255) / 256), 256, 0, stream>>>(w5, FP(o_w5r), 96, 5, 96, t5);
        repack_w<<<dim3((t5 + 255) / 256), 256, 0, stream>>>(w6, FP(o_w6r), 96, 5, 96, t5);
        int t7 = 96 * 3 * 128;
        repack_w<<<dim3((t7 + 255) / 256), 256, 0, stream>>>(w7, FP(o_w7r), 96, 3, 128, t7);
    }

    const int nchunks = 64 / Bc;
    for (int c = 0; c < nchunks; c++) {
        const float* xc = x + (size_t)c * Bc * 40 * 8192;
        int n4 = Bc * 40 * 8192 / 4;
        split_fp32<<<dim3((n4 + 255) / 256), 256, 0, stream>>>(xc, US(o_xh), US(o_xl), n4);

        conv_mfma<16, 10, 40, 256, true, true><<<dim3(Bc * 16), 256, 0, stream>>>(
            US(o_xh), US(o_xl), US(o_wp1), b1, US(o_y1h), US(o_y1l), nullptr, 8192, 4092);
        conv_mfma< 8,  5, 96, 256, true, true><<<dim3(Bc * 8), 256, 0, stream>>>(
            US(o_y1h), US(o_y1l), US(o_wp2), b2, US(o_y2h), US(o_y2l), nullptr, 4092, 2044);
        unsigned short* y3h_c = US(o_y3h) + (size_t)c * Bc * 96 * 1020;
        unsigned short* y3l_c = US(o_y3l) + (size_t)c * Bc * 96 * 1020;
        conv_mfma< 8,  5, 96, 128, true, true><<<dim3(Bc * 8), 256, 0, stream>>>(
            US(o_y2h), US(o_y2l), US(o_wp3), b3, y3h_c, y3l_c, nullptr, 2044, 1020);
    }

    conv_mfma<8, 5, 96, 128, false, false><<<dim3(64 * 4), 256, 0, stream>>>(
        US(o_y3h), US(o_y3l), US(o_wp4), b4, nullptr, nullptr, FP(o_y4), 1020, 508);

    pool2_relu<<<dim3((64 * 96 * 254 + 255) / 256), 256, 0, stream>>>(FP(o_y4), FP(o_y4p), 508, 254, 64 * 96 * 254);
    conv_tile2<5, 96, 96, false><<<dim3(64 * 2), 256, 0, stream>>>(FP(o_y4p), FP(o_w5r), b5, FP(o_y5), 254, 125);
    pool2_relu<<<dim3((64 * 96 * 62 + 255) / 256), 256, 0, stream>>>(FP(o_y5), FP(o_y5p), 125, 62, 64 * 96 * 62);
    conv_tile2<5, 96, 96, true ><<<dim3(64), 256, 0, stream>>>(FP(o_y5p), FP(o_w6r), b6, FP(o_y6), 62, 29);
    conv_tile2<3, 96, 128, true><<<dim3(64), 256, 0, stream>>>(FP(o_y6), FP(o_w7r), b7, FP(o_y7), 29, 14);
    masked_max<<<dim3(32), 256, 0, stream>>>(FP(o_y7), lens, FP(o_ft));
    head_mlp<<<dim3(64), 128, 0, stream>>>(FP(o_ft), lw1, lb1, lw2, lb2, lw3, lb3, out);
}